// Round 6
// baseline (192.780 us; speedup 1.0000x reference)
//
#include <hip/hip_runtime.h>
#include <hip/hip_bf16.h>
#include <math.h>

#define SS 256
#define CC 128
#define NH 4
#define HD 32
#define M_TOT (SS*SS)       // 65536
#define HEAD_STRIDE (M_TOT*HD)
#define PSTR 72             // padded row stride (elems) for P buffer
#define SCALE 0.17677669529663687f
#define QSCL 0.25507602861154995f   // SCALE * log2(e)
#define LOG2E 1.4426950408889634f

typedef short short8 __attribute__((ext_vector_type(8)));
typedef float f32x4 __attribute__((ext_vector_type(4)));
typedef unsigned short ushort_t;

static __device__ __forceinline__ unsigned int f2bf(float f) {
  unsigned int u = __builtin_bit_cast(unsigned int, f);
  u += 0x7fffu + ((u >> 16) & 1u);
  return u >> 16;
}
static __device__ __forceinline__ float bf2f(unsigned short b) {
  unsigned int u = ((unsigned int)b) << 16;
  return __builtin_bit_cast(float, u);
}
static __device__ __forceinline__ unsigned int pack2bf(float a, float b) {
  return f2bf(a) | (f2bf(b) << 16);
}

static __device__ __forceinline__ void async_copy16(const void* g, void* l) {
  __builtin_amdgcn_global_load_lds(
      (const __attribute__((address_space(1))) unsigned int*)g,
      (__attribute__((address_space(3))) unsigned int*)l, 16, 0, 0);
}

// ---------------- LayerNorm (vectorized: 32 lanes/row, float4 in, ushort4 out) ----------------
__global__ __launch_bounds__(256) void ln_kernel(
    const float* __restrict__ x, const float* __restrict__ ln_w,
    const float* __restrict__ ln_b, ushort_t* __restrict__ hbf) {
  int t = threadIdx.x;
  int row = blockIdx.x*8 + (t >> 5);
  int l = t & 31;
  float4 v = *(const float4*)&x[(size_t)row*CC + l*4];
  float s  = v.x + v.y + v.z + v.w;
  float s2 = v.x*v.x + v.y*v.y + v.z*v.z + v.w*v.w;
  #pragma unroll
  for (int o = 16; o > 0; o >>= 1) {
    s  += __shfl_xor(s, o);
    s2 += __shfl_xor(s2, o);
  }
  float mu  = s * (1.0f/CC);
  float var = s2 * (1.0f/CC) - mu*mu;
  float r = rsqrtf(var + 1e-5f);
  float4 w4 = *(const float4*)&ln_w[l*4];
  float4 b4 = *(const float4*)&ln_b[l*4];
  ushort4 o4;
  o4.x = (ushort_t)f2bf((v.x - mu) * r * w4.x + b4.x);
  o4.y = (ushort_t)f2bf((v.y - mu) * r * w4.y + b4.y);
  o4.z = (ushort_t)f2bf((v.z - mu) * r * w4.z + b4.z);
  o4.w = (ushort_t)f2bf((v.w - mu) * r * w4.w + b4.w);
  *(ushort4*)&hbf[(size_t)row*CC + l*4] = o4;
}

// ---------------- pack weights to bf16 ----------------
__global__ __launch_bounds__(256) void pack_w(
    const float* __restrict__ wq, const float* __restrict__ wk,
    const float* __restrict__ wv, const float* __restrict__ wg,
    const float* __restrict__ wb, const float* __restrict__ wo,
    ushort_t* __restrict__ wcomb, ushort_t* __restrict__ wbias,
    ushort_t* __restrict__ wobf) {
  int idx = blockIdx.x*256 + threadIdx.x;
  if (idx >= 656*128) return;
  int n = idx >> 7, kk = idx & 127;
  if (n < 512) {
    float val;
    if (n < 128)      val = wq[n*128 + kk];
    else if (n < 256) val = wk[(n-128)*128 + kk];
    else if (n < 384) val = wv[(n-256)*128 + kk];
    else              val = wg[(n-384)*128 + kk];
    wcomb[idx] = (ushort_t)f2bf(val);
  } else if (n < 528) {
    int r = n - 512;
    wbias[r*128 + kk] = (r < NH) ? (ushort_t)f2bf(wb[r*128 + kk] * LOG2E) : (ushort_t)0;
  } else {
    int r = n - 528;
    wobf[r*128 + kk] = (ushort_t)f2bf(wo[r*128 + kk]);
  }
}

// ---------------- MFMA projection GEMM: [65536 x 128] x [128 x 512] ----------------
// B (one 128x128 section) in LDS; A direct global->VGPR.
// MFMA operands SWAPPED: D^T layout -> lane holds 4 consecutive n -> dwordx2 stores.
__global__ __launch_bounds__(256, 4) void proj_mfma(
    const ushort_t* __restrict__ hbf, const ushort_t* __restrict__ wcomb,
    const ushort_t* __restrict__ wbias,
    ushort_t* __restrict__ qb, ushort_t* __restrict__ kb,
    ushort_t* __restrict__ vb, ushort_t* __restrict__ gbf,
    float* __restrict__ biasF) {
  __shared__ ushort_t Bsh[128*128];   // 32 KB
  int mbase = blockIdx.x * 128;
  int sec = blockIdx.y;
  int tid = threadIdx.x;
  int wvi = tid >> 6, lane = tid & 63;
  int quad = lane >> 4, l15 = lane & 15;

  {
    int lrow4 = lane >> 4;
    int cl = lane & 15;
    #pragma unroll
    for (int t = 0; t < 8; t++) {
      int inst = wvi*8 + t;
      int row = inst*4 + lrow4;
      int gc = cl ^ (row & 7);
      async_copy16(wcomb + (size_t)(sec*128 + row)*128 + gc*8, Bsh + inst*512);
    }
  }
  __syncthreads();

  int wrow = (wvi >> 1) * 64, wcol = (wvi & 1) * 64;
  const f32x4 fz = {0.f,0.f,0.f,0.f};
  f32x4 acc[4][4];
  #pragma unroll
  for (int a = 0; a < 4; a++)
    #pragma unroll
    for (int b = 0; b < 4; b++) acc[a][b] = fz;

  #pragma unroll
  for (int s = 0; s < 4; s++) {
    short8 Af[4], Bf[4];
    #pragma unroll
    for (int f = 0; f < 4; f++) {
      int ra = mbase + wrow + f*16 + l15;
      Af[f] = *(const short8*)&hbf[(size_t)ra*128 + s*32 + quad*8];
      int rb = wcol + f*16 + l15;
      Bf[f] = *(const short8*)&Bsh[rb*128 + (((s*4+quad) ^ (rb&7)) << 3)];
    }
    #pragma unroll
    for (int mi = 0; mi < 4; mi++)
      #pragma unroll
      for (int ni = 0; ni < 4; ni++)
        acc[mi][ni] = __builtin_amdgcn_mfma_f32_16x16x32_bf16(Bf[ni], Af[mi], acc[mi][ni], 0, 0, 0);
  }

  // epilogue (transposed D): lane holds n = wcol+ni*16+quad*4+{0..3} at m = mbase+wrow+mi*16+l15
  #pragma unroll
  for (int mi = 0; mi < 4; mi++) {
    int m = mbase + wrow + mi*16 + l15;
    #pragma unroll
    for (int ni = 0; ni < 4; ni++) {
      int nb = wcol + ni*16 + quad*4;
      f32x4 v = acc[mi][ni];
      if (sec == 3) {
        uint2 pk;
        pk.x = pack2bf(1.0f/(1.0f + __expf(-v[0])), 1.0f/(1.0f + __expf(-v[1])));
        pk.y = pack2bf(1.0f/(1.0f + __expf(-v[2])), 1.0f/(1.0f + __expf(-v[3])));
        *(uint2*)&gbf[(size_t)m*CC + nb] = pk;
      } else {
        float sc = (sec == 0) ? QSCL : 1.0f;
        uint2 pk;
        pk.x = pack2bf(v[0]*sc, v[1]*sc);
        pk.y = pack2bf(v[2]*sc, v[3]*sc);
        ushort_t* dst = (sec == 0) ? qb : (sec == 1) ? kb : vb;
        *(uint2*)&dst[(size_t)(nb>>5)*HEAD_STRIDE + (size_t)m*HD + (nb&31)] = pk;
      }
    }
  }

  // fused bias GEMV (section 0): bias*log2e in MFMA C-fragment order
  if (sec == 0) {
    short8 wbF[4];
    #pragma unroll
    for (int s = 0; s < 4; s++)
      wbF[s] = *(const short8*)&wbias[l15*128 + s*32 + quad*8];
    #pragma unroll
    for (int t2 = 0; t2 < 2; t2++) {
      int f2 = wvi*2 + t2;
      f32x4 bacc = fz;
      #pragma unroll
      for (int s = 0; s < 4; s++) {
        short8 Af = *(const short8*)&hbf[(size_t)(mbase + f2*16 + l15)*128 + s*32 + quad*8];
        bacc = __builtin_amdgcn_mfma_f32_16x16x32_bf16(wbF[s], Af, bacc, 0, 0, 0);
      }
      if (quad == 0) {
        int m = mbase + f2*16 + l15;
        int ji = m >> 8, ki = m & 255;
        int jt = ji >> 4, q2 = (ji >> 2) & 3, rg = ji & 3;
        int kt = ki >> 4, lf = ki & 15;
        #pragma unroll
        for (int r = 0; r < 4; r++)
          biasF[(size_t)(((r*16 + jt)*16 + kt) << 8) + (q2*16 + lf)*4 + rg] = bacc[r];
      }
    }
  }
}

// ---------------- MFMA attention: one block per (i, h), 4 waves ----------------
__global__ __launch_bounds__(256, 3) void attn_mfma(
    const ushort_t* __restrict__ qb, const ushort_t* __restrict__ kb,
    const ushort_t* __restrict__ vb, const float* __restrict__ biasF,
    const ushort_t* __restrict__ gbf, ushort_t* __restrict__ ogated) {
  __shared__ ushort_t Vt[32*256];        // V^T [d][k], XOR-swizzled chunks (16 KB)
  __shared__ ushort_t Pb[4*64*PSTR];     // per-wave P [j][k], padded (36 KB)
  int i = blockIdx.x, hh = blockIdx.y;
  int tid = threadIdx.x;
  int wvi = tid >> 6, lane = tid & 63;
  int quad = lane >> 4, l15 = lane & 15;

  {
    const ushort_t* vrow = vb + ((size_t)hh*M_TOT + (size_t)i*SS + tid) * HD;
    const uint4* v4 = (const uint4*)vrow;
    int cs = tid >> 3, ce = tid & 7;
    #pragma unroll
    for (int c = 0; c < 4; c++) {
      uint4 r = v4[c];
      unsigned int u[4] = {r.x, r.y, r.z, r.w};
      #pragma unroll
      for (int w = 0; w < 4; w++) {
        int d = c*8 + w*2;
        Vt[d*256     + ((cs ^ (d&7))     << 3) + ce] = (ushort_t)(u[w] & 0xffffu);
        Vt[(d+1)*256 + ((cs ^ ((d+1)&7)) << 3) + ce] = (ushort_t)(u[w] >> 16);
      }
    }
  }

  const ushort_t* qbase = qb + ((size_t)hh*M_TOT + (size_t)i*SS + wvi*64) * HD;
  short8 Qf[4];
  #pragma unroll
  for (int a = 0; a < 4; a++)
    Qf[a] = *(const short8*)(qbase + (a*16 + l15)*HD + quad*8);

  const ushort_t* kbp = kb + ((size_t)hh*M_TOT + (size_t)i*SS) * HD;
  const float* bb = biasF + (size_t)(hh*16 + wvi*4) * 4096;

  const f32x4 fz = {0.f, 0.f, 0.f, 0.f};
  f32x4 Oa[4][2];
  #pragma unroll
  for (int a = 0; a < 4; a++) { Oa[a][0] = fz; Oa[a][1] = fz; }
  float lsum[4][4] = {};

  ushort_t* pw = Pb + wvi*64*PSTR;

  __syncthreads();

  #pragma unroll
  for (int it = 0; it < 4; it++) {
    #pragma unroll
    for (int b = 0; b < 4; b++) {
      int kt = it*4 + b;
      short8 Kf = *(const short8*)(kbp + (kt*16 + l15)*HD + quad*8);
      #pragma unroll
      for (int a = 0; a < 4; a++) {
        float4 bt = *(const float4*)(bb + (size_t)((a*16 + kt) << 8) + lane*4);
        f32x4 bias4 = {bt.x, bt.y, bt.z, bt.w};
        f32x4 S = __builtin_amdgcn_mfma_f32_16x16x32_bf16(Qf[a], Kf, bias4, 0, 0, 0);
        float p0 = __builtin_amdgcn_exp2f(S[0]);
        float p1 = __builtin_amdgcn_exp2f(S[1]);
        float p2 = __builtin_amdgcn_exp2f(S[2]);
        float p3 = __builtin_amdgcn_exp2f(S[3]);
        lsum[a][0] += p0; lsum[a][1] += p1; lsum[a][2] += p2; lsum[a][3] += p3;
        ushort_t* pwa = pw + (a*16 + quad*4)*PSTR + b*16 + l15;
        pwa[0*PSTR] = (ushort_t)f2bf(p0);
        pwa[1*PSTR] = (ushort_t)f2bf(p1);
        pwa[2*PSTR] = (ushort_t)f2bf(p2);
        pwa[3*PSTR] = (ushort_t)f2bf(p3);
      }
    }
    #pragma unroll
    for (int kk = 0; kk < 2; kk++) {
      int cb = it*8 + kk*4;
      int sw = ((cb + quad) ^ (l15 & 7)) << 3;
      short8 Vf0 = *(const short8*)&Vt[l15*256 + sw];
      short8 Vf1 = *(const short8*)&Vt[(16 + l15)*256 + sw];
      #pragma unroll
      for (int a = 0; a < 4; a++) {
        short8 Pf = *(const short8*)&pw[(a*16 + l15)*PSTR + kk*32 + quad*8];
        Oa[a][0] = __builtin_amdgcn_mfma_f32_16x16x32_bf16(Pf, Vf0, Oa[a][0], 0, 0, 0);
        Oa[a][1] = __builtin_amdgcn_mfma_f32_16x16x32_bf16(Pf, Vf1, Oa[a][1], 0, 0, 0);
      }
    }
  }

  float linv[4][4];
  #pragma unroll
  for (int a = 0; a < 4; a++) {
    #pragma unroll
    for (int r = 0; r < 4; r++) {
      float v = lsum[a][r];
      v += __shfl_xor(v, 1);
      v += __shfl_xor(v, 2);
      v += __shfl_xor(v, 4);
      v += __shfl_xor(v, 8);
      linv[a][r] = 1.0f / v;
    }
  }
  const ushort_t* gp = gbf + ((size_t)i*SS + wvi*64)*CC + hh*HD;
  ushort_t* ob = ogated + ((size_t)i*SS + wvi*64)*CC + hh*HD;
  #pragma unroll
  for (int a = 0; a < 4; a++) {
    #pragma unroll
    for (int r = 0; r < 4; r++) {
      int row = (a*16 + quad*4 + r) * CC;
      float g0 = bf2f(gp[row + l15]);
      float g1 = bf2f(gp[row + 16 + l15]);
      ob[row + l15]      = (ushort_t)f2bf(Oa[a][0][r] * linv[a][r] * g0);
      ob[row + 16 + l15] = (ushort_t)f2bf(Oa[a][1][r] * linv[a][r] * g1);
    }
  }
}

// ---------------- MFMA output projection: [65536 x 128] x [128 x 128] ----------------
// Swapped operands: float4 stores.
__global__ __launch_bounds__(256, 4) void out_mfma(
    const ushort_t* __restrict__ ogated, const ushort_t* __restrict__ wobf,
    float* __restrict__ out) {
  __shared__ ushort_t Bsh[128*128];   // 32 KB
  int mbase = blockIdx.x * 128;
  int tid = threadIdx.x;
  int wvi = tid >> 6, lane = tid & 63;
  int quad = lane >> 4, l15 = lane & 15;

  {
    int lrow4 = lane >> 4;
    int cl = lane & 15;
    #pragma unroll
    for (int t = 0; t < 8; t++) {
      int inst = wvi*8 + t;
      int row = inst*4 + lrow4;
      int gc = cl ^ (row & 7);
      async_copy16(wobf + (size_t)row*128 + gc*8, Bsh + inst*512);
    }
  }
  __syncthreads();

  int wrow = (wvi >> 1) * 64, wcol = (wvi & 1) * 64;
  const f32x4 fz = {0.f,0.f,0.f,0.f};
  f32x4 acc[4][4];
  #pragma unroll
  for (int a = 0; a < 4; a++)
    #pragma unroll
    for (int b = 0; b < 4; b++) acc[a][b] = fz;

  #pragma unroll
  for (int s = 0; s < 4; s++) {
    short8 Af[4], Bf[4];
    #pragma unroll
    for (int f = 0; f < 4; f++) {
      int ra = mbase + wrow + f*16 + l15;
      Af[f] = *(const short8*)&ogated[(size_t)ra*128 + s*32 + quad*8];
      int rb = wcol + f*16 + l15;
      Bf[f] = *(const short8*)&Bsh[rb*128 + (((s*4+quad) ^ (rb&7)) << 3)];
    }
    #pragma unroll
    for (int mi = 0; mi < 4; mi++)
      #pragma unroll
      for (int ni = 0; ni < 4; ni++)
        acc[mi][ni] = __builtin_amdgcn_mfma_f32_16x16x32_bf16(Bf[ni], Af[mi], acc[mi][ni], 0, 0, 0);
  }

  #pragma unroll
  for (int mi = 0; mi < 4; mi++) {
    int m = mbase + wrow + mi*16 + l15;
    #pragma unroll
    for (int ni = 0; ni < 4; ni++) {
      int nb = wcol + ni*16 + quad*4;
      float4 v4 = make_float4(acc[mi][ni][0], acc[mi][ni][1], acc[mi][ni][2], acc[mi][ni][3]);
      *(float4*)&out[(size_t)m*CC + nb] = v4;
    }
  }
}

extern "C" void kernel_launch(void* const* d_in, const int* in_sizes, int n_in,
                              void* d_out, int out_size, void* d_ws, size_t ws_size,
                              hipStream_t stream) {
  const float* x    = (const float*)d_in[0];
  const float* ln_w = (const float*)d_in[1];
  const float* ln_b = (const float*)d_in[2];
  const float* w_bias = (const float*)d_in[3];
  const float* w_q  = (const float*)d_in[4];
  const float* w_k  = (const float*)d_in[5];
  const float* w_v  = (const float*)d_in[6];
  const float* w_g  = (const float*)d_in[7];
  const float* w_o  = (const float*)d_in[8];
  float* out = (float*)d_out;

  char* B = (char*)d_ws;
  ushort_t* hbf   = (ushort_t*)(B + 0);           // 16 MB (reused as ogated)
  ushort_t* qb    = (ushort_t*)(B + 16777216);    // 16 MB
  ushort_t* kb    = (ushort_t*)(B + 33554432);    // 16 MB
  ushort_t* vb    = (ushort_t*)(B + 50331648);    // 16 MB
  ushort_t* gbf   = (ushort_t*)(B + 67108864);    // 16 MB
  float*    biasF = (float*)   (B + 83886080);    // 1 MB
  ushort_t* wcomb = (ushort_t*)(B + 84934656);    // 128 KB
  ushort_t* wbias = (ushort_t*)(B + 85065728);    // 4 KB
  ushort_t* wobf  = (ushort_t*)(B + 85069824);    // 32 KB
  ushort_t* ogated = hbf;

  ln_kernel<<<M_TOT/8, 256, 0, stream>>>(x, ln_w, ln_b, hbf);
  pack_w<<<(656*128 + 255)/256, 256, 0, stream>>>(w_q, w_k, w_v, w_g, w_bias, w_o,
                                                  wcomb, wbias, wobf);
  proj_mfma<<<dim3(M_TOT/128, 4), 256, 0, stream>>>(hbf, wcomb, wbias,
                                                    qb, kb, vb, gbf, biasF);
  attn_mfma<<<dim3(SS, NH), 256, 0, stream>>>(qb, kb, vb, biasF, gbf, ogated);
  out_mfma<<<M_TOT/128, 256, 0, stream>>>(ogated, wobf, out);
}

// Round 7
// 166.133 us; speedup vs baseline: 1.1604x; 1.1604x over previous
//
#include <hip/hip_runtime.h>
#include <hip/hip_bf16.h>
#include <math.h>

#define SS 256
#define CC 128
#define NH 4
#define HD 32
#define M_TOT (SS*SS)       // 65536
#define HEAD_STRIDE (M_TOT*HD)
#define PSTR 72             // padded row stride (elems) for P buffer
#define SCALE 0.17677669529663687f
#define QSCL 0.25507602861154995f   // SCALE * log2(e)
#define LOG2E 1.4426950408889634f

typedef short short8 __attribute__((ext_vector_type(8)));
typedef float f32x4 __attribute__((ext_vector_type(4)));
typedef unsigned short ushort_t;

static __device__ __forceinline__ unsigned int f2bf(float f) {
  unsigned int u = __builtin_bit_cast(unsigned int, f);
  u += 0x7fffu + ((u >> 16) & 1u);
  return u >> 16;
}
static __device__ __forceinline__ float bf2f(unsigned short b) {
  unsigned int u = ((unsigned int)b) << 16;
  return __builtin_bit_cast(float, u);
}

static __device__ __forceinline__ void async_copy16(const void* g, void* l) {
  __builtin_amdgcn_global_load_lds(
      (const __attribute__((address_space(1))) unsigned int*)g,
      (__attribute__((address_space(3))) unsigned int*)l, 16, 0, 0);
}

// ---------------- pack weights to bf16 ----------------
__global__ __launch_bounds__(256) void pack_w(
    const float* __restrict__ wq, const float* __restrict__ wk,
    const float* __restrict__ wv, const float* __restrict__ wg,
    const float* __restrict__ wb, const float* __restrict__ wo,
    ushort_t* __restrict__ wcomb, ushort_t* __restrict__ wbias,
    ushort_t* __restrict__ wobf) {
  int idx = blockIdx.x*256 + threadIdx.x;
  if (idx >= 656*128) return;
  int n = idx >> 7, kk = idx & 127;
  if (n < 512) {
    float val;
    if (n < 128)      val = wq[n*128 + kk];
    else if (n < 256) val = wk[(n-128)*128 + kk];
    else if (n < 384) val = wv[(n-256)*128 + kk];
    else              val = wg[(n-384)*128 + kk];
    wcomb[idx] = (ushort_t)f2bf(val);
  } else if (n < 528) {
    int r = n - 512;
    wbias[r*128 + kk] = (r < NH) ? (ushort_t)f2bf(wb[r*128 + kk] * LOG2E) : (ushort_t)0;
  } else {
    int r = n - 528;
    wobf[r*128 + kk] = (ushort_t)f2bf(wo[r*128 + kk]);
  }
}

// ---------------- Fused LN + projection GEMM + bias GEMV ----------------
// One block per 128-row tile. LN(x) -> Ash (swizzled bf16, stays resident);
// loop 4 weight sections through a single 32 KB Bsh with async prefetch
// overlapped against the previous section's epilogue stores.
__global__ __launch_bounds__(256, 2) void fused_proj(
    const float* __restrict__ x, const float* __restrict__ ln_w,
    const float* __restrict__ ln_b, const ushort_t* __restrict__ wcomb,
    const ushort_t* __restrict__ wbias,
    ushort_t* __restrict__ qb, ushort_t* __restrict__ kb,
    ushort_t* __restrict__ vb, ushort_t* __restrict__ gbf,
    float* __restrict__ biasF) {
  __shared__ ushort_t Ash[128*128];   // 32 KB, LN output, swizzled
  __shared__ ushort_t Bsh[128*128];   // 32 KB, current weight section
  int mbase = blockIdx.x * 128;
  int tid = threadIdx.x;
  int wvi = tid >> 6, lane = tid & 63;
  int quad = lane >> 4, l15 = lane & 15;
  int lrow4 = lane >> 4;
  int cl = lane & 15;

  // prefetch B section 0 while LN runs
  #pragma unroll
  for (int t = 0; t < 8; t++) {
    int inst = wvi*8 + t;
    int row = inst*4 + lrow4;
    int gc = cl ^ (row & 7);
    async_copy16(wcomb + (size_t)row*128 + gc*8, Bsh + inst*512);
  }

  // ---- LayerNorm phase: 32 lanes per row, 8 rows/pass, 16 passes ----
  {
    int l = tid & 31;
    int rsub = tid >> 5;              // 0..7
    float4 w4 = *(const float4*)&ln_w[l*4];
    float4 b4 = *(const float4*)&ln_b[l*4];
    #pragma unroll
    for (int pass = 0; pass < 16; pass++) {
      int row = pass*8 + rsub;        // 0..127 within tile
      float4 v = *(const float4*)&x[(size_t)(mbase + row)*CC + l*4];
      float s  = v.x + v.y + v.z + v.w;
      float s2 = v.x*v.x + v.y*v.y + v.z*v.z + v.w*v.w;
      #pragma unroll
      for (int o = 16; o > 0; o >>= 1) {
        s  += __shfl_xor(s, o);
        s2 += __shfl_xor(s2, o);
      }
      float mu  = s * (1.0f/CC);
      float var = s2 * (1.0f/CC) - mu*mu;
      float r = rsqrtf(var + 1e-5f);
      ushort4 o4;
      o4.x = (ushort_t)f2bf((v.x - mu) * r * w4.x + b4.x);
      o4.y = (ushort_t)f2bf((v.y - mu) * r * w4.y + b4.y);
      o4.z = (ushort_t)f2bf((v.z - mu) * r * w4.z + b4.z);
      o4.w = (ushort_t)f2bf((v.w - mu) * r * w4.w + b4.w);
      // swizzled store: element chunk = l>>1, chunk' = chunk ^ (row&7)
      int addr = row*128 + (((l >> 1) ^ (row & 7)) << 3) + (l & 1)*4;
      *(ushort4*)&Ash[addr] = o4;
    }
  }
  __syncthreads();   // Ash complete + B0 staged (vmcnt drained by barrier)

  int wrow = (wvi >> 1) * 64, wcol = (wvi & 1) * 64;
  const f32x4 fz = {0.f,0.f,0.f,0.f};

  // A fragments are section-invariant: load once
  short8 Afr[4][4];   // [s][f]
  #pragma unroll
  for (int s = 0; s < 4; s++)
    #pragma unroll
    for (int f = 0; f < 4; f++) {
      int ra = wrow + f*16 + l15;
      Afr[s][f] = *(const short8*)&Ash[ra*128 + (((s*4+quad) ^ (ra&7)) << 3)];
    }

  #pragma unroll
  for (int sec = 0; sec < 4; sec++) {
    f32x4 acc[4][4];
    #pragma unroll
    for (int a = 0; a < 4; a++)
      #pragma unroll
      for (int b = 0; b < 4; b++) acc[a][b] = fz;

    #pragma unroll
    for (int s = 0; s < 4; s++) {
      short8 Bf[4];
      #pragma unroll
      for (int f = 0; f < 4; f++) {
        int rb = wcol + f*16 + l15;
        Bf[f] = *(const short8*)&Bsh[rb*128 + (((s*4+quad) ^ (rb&7)) << 3)];
      }
      #pragma unroll
      for (int mi = 0; mi < 4; mi++)
        #pragma unroll
        for (int ni = 0; ni < 4; ni++)
          acc[mi][ni] = __builtin_amdgcn_mfma_f32_16x16x32_bf16(Afr[s][mi], Bf[ni], acc[mi][ni], 0, 0, 0);
    }

    __syncthreads();   // all waves done reading Bsh[sec]

    if (sec < 3) {     // prefetch next section; overlaps epilogue stores
      #pragma unroll
      for (int t = 0; t < 8; t++) {
        int inst = wvi*8 + t;
        int row = inst*4 + lrow4;
        int gc = cl ^ (row & 7);
        async_copy16(wcomb + (size_t)((sec+1)*128 + row)*128 + gc*8, Bsh + inst*512);
      }
    }

    // epilogue: m = mbase+wrow+mi*16+quad*4+r, n = wcol+ni*16+l15
    #pragma unroll
    for (int mi = 0; mi < 4; mi++) {
      #pragma unroll
      for (int r = 0; r < 4; r++) {
        int m = mbase + wrow + mi*16 + quad*4 + r;
        #pragma unroll
        for (int ni = 0; ni < 4; ni++) {
          int n = wcol + ni*16 + l15;
          float v = acc[mi][ni][r];
          if (sec == 0) {
            qb[(size_t)(n>>5)*HEAD_STRIDE + (size_t)m*HD + (n&31)] = (ushort_t)f2bf(v * QSCL);
          } else if (sec == 1) {
            kb[(size_t)(n>>5)*HEAD_STRIDE + (size_t)m*HD + (n&31)] = (ushort_t)f2bf(v);
          } else if (sec == 2) {
            vb[(size_t)(n>>5)*HEAD_STRIDE + (size_t)m*HD + (n&31)] = (ushort_t)f2bf(v);
          } else {
            gbf[(size_t)m*CC + n] = (ushort_t)f2bf(1.0f/(1.0f + __expf(-v)));
          }
        }
      }
    }

    if (sec == 0) {
      // fused bias GEMV: bias*log2e in MFMA C-fragment order
      short8 wbF[4];
      #pragma unroll
      for (int s = 0; s < 4; s++)
        wbF[s] = *(const short8*)&wbias[l15*128 + s*32 + quad*8];
      #pragma unroll
      for (int t2 = 0; t2 < 2; t2++) {
        int f2 = wvi*2 + t2;
        f32x4 bacc = fz;
        #pragma unroll
        for (int s = 0; s < 4; s++) {
          int ra = f2*16 + l15;
          short8 Af = *(const short8*)&Ash[ra*128 + (((s*4+quad) ^ (ra&7)) << 3)];
          bacc = __builtin_amdgcn_mfma_f32_16x16x32_bf16(wbF[s], Af, bacc, 0, 0, 0);
        }
        if (quad == 0) {
          int m = mbase + f2*16 + l15;
          int ji = m >> 8, ki = m & 255;
          int jt = ji >> 4, q2 = (ji >> 2) & 3, rg = ji & 3;
          int kt = ki >> 4, lf = ki & 15;
          #pragma unroll
          for (int r = 0; r < 4; r++)
            biasF[(size_t)(((r*16 + jt)*16 + kt) << 8) + (q2*16 + lf)*4 + rg] = bacc[r];
        }
      }
    }

    if (sec < 3) __syncthreads();   // next Bsh staged before its MFMAs
  }
}

// ---------------- MFMA attention: one block per (i, h), 4 waves ----------------
__global__ __launch_bounds__(256, 3) void attn_mfma(
    const ushort_t* __restrict__ qb, const ushort_t* __restrict__ kb,
    const ushort_t* __restrict__ vb, const float* __restrict__ biasF,
    const ushort_t* __restrict__ gbf, ushort_t* __restrict__ ogated) {
  __shared__ ushort_t Vt[32*256];        // V^T [d][k], XOR-swizzled chunks (16 KB)
  __shared__ ushort_t Pb[4*64*PSTR];     // per-wave P [j][k], padded (36 KB)
  int i = blockIdx.x, hh = blockIdx.y;
  int tid = threadIdx.x;
  int wvi = tid >> 6, lane = tid & 63;
  int quad = lane >> 4, l15 = lane & 15;

  {
    const ushort_t* vrow = vb + ((size_t)hh*M_TOT + (size_t)i*SS + tid) * HD;
    const uint4* v4 = (const uint4*)vrow;
    int cs = tid >> 3, ce = tid & 7;
    #pragma unroll
    for (int c = 0; c < 4; c++) {
      uint4 r = v4[c];
      unsigned int u[4] = {r.x, r.y, r.z, r.w};
      #pragma unroll
      for (int w = 0; w < 4; w++) {
        int d = c*8 + w*2;
        Vt[d*256     + ((cs ^ (d&7))     << 3) + ce] = (ushort_t)(u[w] & 0xffffu);
        Vt[(d+1)*256 + ((cs ^ ((d+1)&7)) << 3) + ce] = (ushort_t)(u[w] >> 16);
      }
    }
  }

  const ushort_t* qbase = qb + ((size_t)hh*M_TOT + (size_t)i*SS + wvi*64) * HD;
  short8 Qf[4];
  #pragma unroll
  for (int a = 0; a < 4; a++)
    Qf[a] = *(const short8*)(qbase + (a*16 + l15)*HD + quad*8);

  const ushort_t* kbp = kb + ((size_t)hh*M_TOT + (size_t)i*SS) * HD;
  const float* bb = biasF + (size_t)(hh*16 + wvi*4) * 4096;

  const f32x4 fz = {0.f, 0.f, 0.f, 0.f};
  f32x4 Oa[4][2];
  #pragma unroll
  for (int a = 0; a < 4; a++) { Oa[a][0] = fz; Oa[a][1] = fz; }
  float lsum[4][4] = {};

  ushort_t* pw = Pb + wvi*64*PSTR;

  __syncthreads();

  #pragma unroll
  for (int it = 0; it < 4; it++) {
    #pragma unroll
    for (int b = 0; b < 4; b++) {
      int kt = it*4 + b;
      short8 Kf = *(const short8*)(kbp + (kt*16 + l15)*HD + quad*8);
      #pragma unroll
      for (int a = 0; a < 4; a++) {
        float4 bt = *(const float4*)(bb + (size_t)((a*16 + kt) << 8) + lane*4);
        f32x4 bias4 = {bt.x, bt.y, bt.z, bt.w};
        f32x4 S = __builtin_amdgcn_mfma_f32_16x16x32_bf16(Qf[a], Kf, bias4, 0, 0, 0);
        float p0 = __builtin_amdgcn_exp2f(S[0]);
        float p1 = __builtin_amdgcn_exp2f(S[1]);
        float p2 = __builtin_amdgcn_exp2f(S[2]);
        float p3 = __builtin_amdgcn_exp2f(S[3]);
        lsum[a][0] += p0; lsum[a][1] += p1; lsum[a][2] += p2; lsum[a][3] += p3;
        ushort_t* pwa = pw + (a*16 + quad*4)*PSTR + b*16 + l15;
        pwa[0*PSTR] = (ushort_t)f2bf(p0);
        pwa[1*PSTR] = (ushort_t)f2bf(p1);
        pwa[2*PSTR] = (ushort_t)f2bf(p2);
        pwa[3*PSTR] = (ushort_t)f2bf(p3);
      }
    }
    #pragma unroll
    for (int kk = 0; kk < 2; kk++) {
      int cb = it*8 + kk*4;
      int sw = ((cb + quad) ^ (l15 & 7)) << 3;
      short8 Vf0 = *(const short8*)&Vt[l15*256 + sw];
      short8 Vf1 = *(const short8*)&Vt[(16 + l15)*256 + sw];
      #pragma unroll
      for (int a = 0; a < 4; a++) {
        short8 Pf = *(const short8*)&pw[(a*16 + l15)*PSTR + kk*32 + quad*8];
        Oa[a][0] = __builtin_amdgcn_mfma_f32_16x16x32_bf16(Pf, Vf0, Oa[a][0], 0, 0, 0);
        Oa[a][1] = __builtin_amdgcn_mfma_f32_16x16x32_bf16(Pf, Vf1, Oa[a][1], 0, 0, 0);
      }
    }
  }

  float linv[4][4];
  #pragma unroll
  for (int a = 0; a < 4; a++) {
    #pragma unroll
    for (int r = 0; r < 4; r++) {
      float v = lsum[a][r];
      v += __shfl_xor(v, 1);
      v += __shfl_xor(v, 2);
      v += __shfl_xor(v, 4);
      v += __shfl_xor(v, 8);
      linv[a][r] = 1.0f / v;
    }
  }
  const ushort_t* gp = gbf + ((size_t)i*SS + wvi*64)*CC + hh*HD;
  ushort_t* ob = ogated + ((size_t)i*SS + wvi*64)*CC + hh*HD;
  #pragma unroll
  for (int a = 0; a < 4; a++) {
    #pragma unroll
    for (int r = 0; r < 4; r++) {
      int row = (a*16 + quad*4 + r) * CC;
      float g0 = bf2f(gp[row + l15]);
      float g1 = bf2f(gp[row + 16 + l15]);
      ob[row + l15]      = (ushort_t)f2bf(Oa[a][0][r] * linv[a][r] * g0);
      ob[row + 16 + l15] = (ushort_t)f2bf(Oa[a][1][r] * linv[a][r] * g1);
    }
  }
}

// ---------------- MFMA output projection: [65536 x 128] x [128 x 128] ----------------
__global__ __launch_bounds__(256, 3) void out_mfma(
    const ushort_t* __restrict__ ogated, const ushort_t* __restrict__ wobf,
    float* __restrict__ out) {
  __shared__ ushort_t Bsh[128*128];   // 32 KB
  int mbase = blockIdx.x * 128;
  int tid = threadIdx.x;
  int wvi = tid >> 6, lane = tid & 63;
  int quad = lane >> 4, l15 = lane & 15;

  {
    int lrow4 = lane >> 4;
    int cl = lane & 15;
    #pragma unroll
    for (int t = 0; t < 8; t++) {
      int inst = wvi*8 + t;
      int row = inst*4 + lrow4;
      int gc = cl ^ (row & 7);
      async_copy16(wobf + (size_t)row*128 + gc*8, Bsh + inst*512);
    }
  }
  __syncthreads();

  int wrow = (wvi >> 1) * 64, wcol = (wvi & 1) * 64;
  const f32x4 fz = {0.f,0.f,0.f,0.f};
  f32x4 acc[4][4];
  #pragma unroll
  for (int a = 0; a < 4; a++)
    #pragma unroll
    for (int b = 0; b < 4; b++) acc[a][b] = fz;

  #pragma unroll
  for (int s = 0; s < 4; s++) {
    short8 Af[4], Bf[4];
    #pragma unroll
    for (int f = 0; f < 4; f++) {
      int ra = mbase + wrow + f*16 + l15;
      Af[f] = *(const short8*)&ogated[(size_t)ra*128 + s*32 + quad*8];
      int rb = wcol + f*16 + l15;
      Bf[f] = *(const short8*)&Bsh[rb*128 + (((s*4+quad) ^ (rb&7)) << 3)];
    }
    #pragma unroll
    for (int mi = 0; mi < 4; mi++)
      #pragma unroll
      for (int ni = 0; ni < 4; ni++)
        acc[mi][ni] = __builtin_amdgcn_mfma_f32_16x16x32_bf16(Af[mi], Bf[ni], acc[mi][ni], 0, 0, 0);
  }

  #pragma unroll
  for (int mi = 0; mi < 4; mi++) {
    #pragma unroll
    for (int r = 0; r < 4; r++) {
      int m = mbase + wrow + mi*16 + quad*4 + r;
      #pragma unroll
      for (int ni = 0; ni < 4; ni++) {
        int n = wcol + ni*16 + l15;
        out[(size_t)m*CC + n] = acc[mi][ni][r];
      }
    }
  }
}

extern "C" void kernel_launch(void* const* d_in, const int* in_sizes, int n_in,
                              void* d_out, int out_size, void* d_ws, size_t ws_size,
                              hipStream_t stream) {
  const float* x    = (const float*)d_in[0];
  const float* ln_w = (const float*)d_in[1];
  const float* ln_b = (const float*)d_in[2];
  const float* w_bias = (const float*)d_in[3];
  const float* w_q  = (const float*)d_in[4];
  const float* w_k  = (const float*)d_in[5];
  const float* w_v  = (const float*)d_in[6];
  const float* w_g  = (const float*)d_in[7];
  const float* w_o  = (const float*)d_in[8];
  float* out = (float*)d_out;

  char* B = (char*)d_ws;
  ushort_t* ogated = (ushort_t*)(B + 0);          // 16 MB
  ushort_t* qb    = (ushort_t*)(B + 16777216);    // 16 MB
  ushort_t* kb    = (ushort_t*)(B + 33554432);    // 16 MB
  ushort_t* vb    = (ushort_t*)(B + 50331648);    // 16 MB
  ushort_t* gbf   = (ushort_t*)(B + 67108864);    // 16 MB
  float*    biasF = (float*)   (B + 83886080);    // 1 MB
  ushort_t* wcomb = (ushort_t*)(B + 84934656);    // 128 KB
  ushort_t* wbias = (ushort_t*)(B + 85065728);    // 4 KB
  ushort_t* wobf  = (ushort_t*)(B + 85069824);    // 32 KB

  pack_w<<<(656*128 + 255)/256, 256, 0, stream>>>(w_q, w_k, w_v, w_g, w_bias, w_o,
                                                  wcomb, wbias, wobf);
  fused_proj<<<M_TOT/128, 256, 0, stream>>>(x, ln_w, ln_b, wcomb, wbias,
                                            qb, kb, vb, gbf, biasF);
  attn_mfma<<<dim3(SS, NH), 256, 0, stream>>>(qb, kb, vb, biasF, gbf, ogated);
  out_mfma<<<M_TOT/128, 256, 0, stream>>>(ogated, wobf, out);
}